// Round 14
// baseline (72.496 us; speedup 1.0000x reference)
//
#include <hip/hip_runtime.h>

#define THREADS 512
#define PB 12                        // puzzles per block
#define CELLS_PB (PB * 81)           // 972 cells
#define TOTW (CELLS_PB * 9)          // 8748 words staged (35 KB)
#define NF4 (TOTW / 4)               // 2187 float4
#define WLANES 486                   // phase-A lanes, 2 cells each (95% packing)

typedef float f4 __attribute__((ext_vector_type(4)));
typedef float f2 __attribute__((ext_vector_type(2)));
typedef __fp16 h2 __attribute__((ext_vector_type(2)));
typedef unsigned int u32;
typedef u32 u2 __attribute__((ext_vector_type(2)));
typedef int i2 __attribute__((ext_vector_type(2)));

#define LOG2E 1.44269504f
#define LN2   0.69314718f

static __device__ __forceinline__ u32 pkrtz(float a, float b) {
  h2 v = __builtin_amdgcn_cvt_pkrtz(a, b);     // v_cvt_pkrtz_f16_f32
  return __builtin_bit_cast(u32, v);
}

__global__ __launch_bounds__(THREADS, 8) void sudoku_main(
    const float* __restrict__ logits,
    const int*   __restrict__ targets,
    const int*   __restrict__ puzzles,
    float* __restrict__ partial,      // [5][ngrid], per-block partials (no atomics)
    int B, int ngrid)
{
  __shared__ float buf[TOTW];         // staged logits f32 -> probs f16x2 in place
  __shared__ float sred[8][5];

  const int tid = threadIdx.x;
  const int g   = blockIdx.x;
  const long totalCells = (long)B * 81;
  const long lim4 = totalCells * 9 / 4;

  float a_focal=0.f, a_ent=0.f, a_msk=0.f, a_uniq=0.f, a_sq=0.f;

  // ---- stage logits: 4 full 512-lane f4 rounds + 139 tail (all dense) ----
  {
    const f4* src = (const f4*)logits;
    const long b4 = (long)g * NF4;
    f4* dst = (f4*)buf;
#pragma unroll
    for (int r = 0; r < 4; ++r) {
      long idx = b4 + r * THREADS + tid;
      if (idx < lim4) dst[r * THREADS + tid] = src[idx];
    }
    if (tid < NF4 - 4 * THREADS) {               // 139 remaining f4
      long idx = b4 + 4 * THREADS + tid;
      if (idx < lim4) dst[4 * THREADS + tid] = src[idx];
    }
  }

  // ---- per-lane int loads: 2 cells as one i2 (dense lines) ----
  const long cell0 = (long)g * CELLS_PB + 2 * tid;
  const bool vA = (tid < WLANES) && (cell0 < totalCells);
  i2 tg2{}, pz2{};
  if (vA) {
    tg2 = *(const i2*)(targets + cell0);
    pz2 = *(const i2*)(puzzles + cell0);
  }
  __syncthreads();

  // ---- phase A: read own 72B slice (9x b64), 2 cells in regs ----
  if (vA) {
    f2 v[9];
    const f2* xp = (const f2*)(buf + 18 * tid);  // byte 72t: 8B-aligned
#pragma unroll
    for (int q = 0; q < 9; ++q) v[q] = xp[q];

    u32 q5[2][5];
#pragma unroll
    for (int k = 0; k < 2; ++k) {
      float l[9];
#pragma unroll
      for (int i = 0; i < 9; ++i) { const int w = 9 * k + i; l[i] = v[w >> 1][w & 1]; }
      int tg = ((k == 0) ? tg2[0] : tg2[1]) - 1; tg = tg < 0 ? 0 : (tg > 8 ? 8 : tg);
      const int pz = (k == 0) ? pz2[0] : pz2[1];

      float t1 = l[0], t2 = -3.0e38f;            // branchless top-2 of logits
#pragma unroll
      for (int i = 1; i < 9; ++i) {
        float hi = fmaxf(t1, l[i]);
        float lo = fminf(t1, l[i]);
        t1 = hi; t2 = fmaxf(t2, lo);
      }
      const float t1b = t1 * LOG2E;
      float e[9], ssum = 0.f, lsum2 = 0.f, x2tg = 0.f;
#pragma unroll
      for (int i = 0; i < 9; ++i) {
        float x2 = fmaf(l[i], LOG2E, -t1b);      // (l-t1)*log2e, one fma
        float ei = __builtin_amdgcn_exp2f(x2);   // v_exp_f32 is 2^x
        e[i] = ei; ssum += ei;
        lsum2 = fmaf(ei, x2, lsum2);
        x2tg = (tg == i) ? x2 : x2tg;            // static-index select ladder
      }
      float inv_s = __builtin_amdgcn_rcpf(ssum);
      float logs2 = __builtin_amdgcn_logf(ssum); // v_log_f32 is log2
      float lptb  = x2tg - logs2;                // log2(p_target)
      float pt    = __builtin_amdgcn_exp2f(lptb);
      float om    = 1.f - pt;
      float focal = om * om * (-lptb * LN2);
      float ent   = (logs2 - lsum2 * inv_s) * LN2;
      float g2    = __builtin_amdgcn_exp2f(fmaf(t2, LOG2E, -t1b));   // exp(t2-t1)
      float gap   = (1.f - g2) * inv_s;
      float uq    = fmaxf(0.f, 1.f - gap);
      float mk    = (pz == 0) ? 1.f : 0.f;
      a_focal += focal * mk;
      a_ent   += ent * mk;
      a_msk   += mk;
      a_uniq  += uq;                             // uniqueness is unmasked
      float pm = inv_s * mk;
      q5[k][0] = pkrtz(e[0]*pm, e[1]*pm);
      q5[k][1] = pkrtz(e[2]*pm, e[3]*pm);
      q5[k][2] = pkrtz(e[4]*pm, e[5]*pm);
      q5[k][3] = pkrtz(e[6]*pm, e[7]*pm);
      q5[k][4] = pkrtz(e[8]*pm, 0.f);
    }
    // overwrite own slice: cells 2t,2t+1 -> words 18t..18t+4, 18t+9..18t+13
    u32* wp = (u32*)(buf + 18 * tid);
    { u2 a; a[0]=q5[0][0]; a[1]=q5[0][1]; *(u2*)(wp + 0) = a; }
    { u2 a; a[0]=q5[0][2]; a[1]=q5[0][3]; *(u2*)(wp + 2) = a; }
    wp[4] = q5[0][4];
    wp[9] = q5[1][0];
    { u2 a; a[0]=q5[1][1]; a[1]=q5[1][2]; *(u2*)(wp + 10) = a; }
    { u2 a; a[0]=q5[1][3]; a[1]=q5[1][4]; *(u2*)(wp + 12) = a; }
  }
  __syncthreads();

  // ---- phase C: 60 workers over ALL 8 waves (8 lanes/wave) ----
  const int wv = tid >> 6, lane = tid & 63;
  if (lane < 8) {
    const int q = wv * 8 + lane;                 // 0..63, workers are q<60
    if (q < PB * 5) {
      const int pz = q / 5, pr = q % 5;
      if ((long)g * PB + pz < (long)B) {
        const u32* cb = (const u32*)buf;
        h2 hz; hz[0] = (__fp16)0.f; hz[1] = (__fp16)0.f;
        h2 rs[9], cs[9], bs[9];
#pragma unroll
        for (int u = 0; u < 9; ++u) { rs[u] = hz; cs[u] = hz; bs[u] = hz; }
        const int base = pz * 729 + pr;          // word (pz*81+j)*9 + pr
#pragma unroll
        for (int j = 0; j < 81; ++j) {
          h2 pv = __builtin_bit_cast(h2, cb[base + 9 * j]);
          rs[j / 9]                      += pv;
          cs[j % 9]                      += pv;
          bs[(j / 27) * 3 + (j % 9) / 3] += pv;
        }
        const float hiw = (pr == 4) ? 0.f : 1.f; // pad class excluded
        float sq = 0.f;
#pragma unroll
        for (int u = 0; u < 9; ++u) {
          float x;
          x = (float)rs[u][0] - 1.f; sq = fmaf(x, x, sq);
          x = (float)cs[u][0] - 1.f; sq = fmaf(x, x, sq);
          x = (float)bs[u][0] - 1.f; sq = fmaf(x, x, sq);
          x = (float)rs[u][1] - 1.f; sq = fmaf(hiw * x, x, sq);
          x = (float)cs[u][1] - 1.f; sq = fmaf(hiw * x, x, sq);
          x = (float)bs[u][1] - 1.f; sq = fmaf(hiw * x, x, sq);
        }
        a_sq += sq;
      }
    }
  }

  // ---- wave + block reduction, transposed partial store (no atomics) ----
#pragma unroll
  for (int off = 32; off > 0; off >>= 1) {
    a_focal += __shfl_down(a_focal, off);
    a_ent   += __shfl_down(a_ent,   off);
    a_msk   += __shfl_down(a_msk,   off);
    a_uniq  += __shfl_down(a_uniq,  off);
    a_sq    += __shfl_down(a_sq,    off);
  }
  if (lane == 0) {
    sred[wv][0] = a_focal; sred[wv][1] = a_ent; sred[wv][2] = a_msk;
    sred[wv][3] = a_uniq;  sred[wv][4] = a_sq;
  }
  __syncthreads();
  if (tid < 5) {
    float s = 0.f;
#pragma unroll
    for (int w = 0; w < 8; ++w) s += sred[w][tid];
    partial[(size_t)tid * ngrid + g] = s;
  }
}

__global__ __launch_bounds__(1024) void sudoku_finalize(
    const float* __restrict__ partial, float* __restrict__ out,
    int ngrid, float invBG)
{
  __shared__ float sb[16][5];
  const int tid = threadIdx.x;
  float s[5] = {0.f, 0.f, 0.f, 0.f, 0.f};
  for (int b = tid; b < ngrid; b += 1024) {
#pragma unroll
    for (int u = 0; u < 5; ++u) s[u] += partial[(size_t)u * ngrid + b];   // coalesced
  }
#pragma unroll
  for (int off = 32; off > 0; off >>= 1)
#pragma unroll
    for (int u = 0; u < 5; ++u) s[u] += __shfl_down(s[u], off);
  const int wv = tid >> 6, lane = tid & 63;
  if (lane == 0) {
#pragma unroll
    for (int u = 0; u < 5; ++u) sb[wv][u] = s[u];
  }
  __syncthreads();
  if (tid == 0) {
    float focal = 0.f, ent = 0.f, msum = 0.f, uniq = 0.f, sq = 0.f;
#pragma unroll
    for (int w = 0; w < 16; ++w) {
      focal += sb[w][0]; ent += sb[w][1]; msum += sb[w][2];
      uniq  += sb[w][3]; sq  += sb[w][4];
    }
    float inv_m = 1.f / (msum + 1e-8f);
    float ce    = focal * inv_m;
    float entl  = 0.1f * ent * inv_m;
    float uql   = 0.1f * uniq * invBG;
    float rcb   = sq * invBG;        // row+col+box means share denominator B*81
    float constraint = (rcb + entl + uql) * 0.2f;
    out[0] = ce + 0.5f * constraint;
  }
}

extern "C" void kernel_launch(void* const* d_in, const int* in_sizes, int n_in,
                              void* d_out, int out_size, void* d_ws, size_t ws_size,
                              hipStream_t stream)
{
  (void)n_in; (void)out_size; (void)ws_size;
  const float* logits  = (const float*)d_in[0];
  const int*   targets = (const int*)d_in[1];
  const int*   puzzles = (const int*)d_in[2];
  float* out = (float*)d_out;
  float* partial = (float*)d_ws;

  const int B = in_sizes[0] / 729;               // B*9*9*9 logits
  const long totalCells = (long)B * 81;
  const int ngrid = (int)((totalCells + CELLS_PB - 1) / CELLS_PB);   // 5462 @ B=65536

  sudoku_main<<<ngrid, THREADS, 0, stream>>>(logits, targets, puzzles, partial, B, ngrid);

  const float invBG = 1.f / ((float)B * 81.f);
  sudoku_finalize<<<1, 1024, 0, stream>>>(partial, out, ngrid, invBG);
}

// Round 15
// 68.451 us; speedup vs baseline: 1.0591x; 1.0591x over previous
//
#include <hip/hip_runtime.h>

#define THREADS 256
#define PB 12                        // puzzles per chunk
#define CELLS_PB (PB * 81)           // 972 cells
#define CHW (CELLS_PB * 9)           // 8748 words
#define CHF4 (CHW / 4)               // 2187 f4 per chunk
#define PADF4 2304                   // 9 uniform rounds x 256 lanes
#define MAXG 512                     // 2 blocks/CU (73.7 KB LDS)

typedef float f4 __attribute__((ext_vector_type(4)));
typedef __fp16 h2 __attribute__((ext_vector_type(2)));
typedef unsigned int u32;
typedef int i4 __attribute__((ext_vector_type(4)));

static __device__ __forceinline__ u32 pkrtz(float a, float b) {
  h2 v = __builtin_amdgcn_cvt_pkrtz(a, b);     // v_cvt_pkrtz_f16_f32
  return __builtin_bit_cast(u32, v);
}
static __device__ __forceinline__ void gload_lds16(const f4* g, f4* l) {
  __builtin_amdgcn_global_load_lds(
      (const __attribute__((address_space(1))) void*)g,
      (__attribute__((address_space(3))) void*)l, 16, 0, 0);
}
#define WAITV11() do { asm volatile("s_waitcnt vmcnt(11)" ::: "memory"); \
                       __builtin_amdgcn_sched_barrier(0); } while (0)
#define WAITV0()  do { asm volatile("s_waitcnt vmcnt(0)"  ::: "memory"); \
                       __builtin_amdgcn_sched_barrier(0); } while (0)
#define WAITL0()  do { asm volatile("s_waitcnt lgkmcnt(0)" ::: "memory"); \
                       __builtin_amdgcn_sched_barrier(0); } while (0)
#define BAR()     do { asm volatile("" ::: "memory"); __builtin_amdgcn_s_barrier(); \
                       asm volatile("" ::: "memory"); \
                       __builtin_amdgcn_sched_barrier(0); } while (0)

// issue chunk c: 9 glds rounds + 2 int4 loads = EXACTLY 11 VMEM ops per lane/wave
static __device__ __forceinline__ void issue_chunk(
    const f4* __restrict__ src, const int* __restrict__ targets,
    const int* __restrict__ puzzles, f4* lbuf, long c, long totF4,
    long maxCell0, int tid, i4& tg4, i4& pz4)
{
  const long b4 = c * CHF4;
  if (b4 + PADF4 <= totF4) {                   // fast path: no clamping
#pragma unroll
    for (int r = 0; r < 9; ++r)
      gload_lds16(src + b4 + r * 256 + tid, lbuf + r * 256 + tid);
  } else {
    const long lim = totF4 - 1;
#pragma unroll
    for (int r = 0; r < 9; ++r) {
      long idx = b4 + r * 256 + tid;
      idx = idx < lim ? idx : lim;             // clamp: always issue (uniform count)
      gload_lds16(src + idx, lbuf + r * 256 + tid);
    }
  }
  long cell0 = c * CELLS_PB + 4 * tid;
  cell0 = cell0 < maxCell0 ? cell0 : maxCell0;
  tg4 = *(const i4*)(targets + cell0);
  pz4 = *(const i4*)(puzzles + cell0);
}

static __device__ __forceinline__ void phaseA(
    f4* lbuf, const i4& tg4, const i4& pz4, long c, long totalCells, int tid,
    float& a_focal, float& a_ent, float& a_msk, float& a_uniq)
{
  const long rem = totalCells - c * CELLS_PB;  // cells in this chunk (mult of 4)
  if (tid < 243 && (long)(4 * tid) < rem) {
    f4 s[9];
#pragma unroll
    for (int q = 0; q < 9; ++q) s[q] = lbuf[tid * 9 + q];
#pragma unroll
    for (int k = 0; k < 4; ++k) {
      float l[9];
#pragma unroll
      for (int i = 0; i < 9; ++i) { const int w = 9 * k + i; l[i] = s[w >> 2][w & 3]; }
      int tg = tg4[k] - 1; tg = tg < 0 ? 0 : (tg > 8 ? 8 : tg);

      float t1 = l[0], t2 = -3.0e38f;          // branchless top-2 of logits
#pragma unroll
      for (int i = 1; i < 9; ++i) {
        float hi = fmaxf(t1, l[i]);
        float lo = fminf(t1, l[i]);
        t1 = hi; t2 = fmaxf(t2, lo);
      }
      float e[9], ssum = 0.f, lsum = 0.f, ltg = l[0];
#pragma unroll
      for (int i = 0; i < 9; ++i) {
        float x  = l[i] - t1;
        float ei = __expf(x);
        e[i] = ei; ssum += ei;
        lsum = fmaf(ei, x, lsum);
        if (i > 0) ltg = (tg == i) ? l[i] : ltg;
      }
      float inv_s = __builtin_amdgcn_rcpf(ssum);
      float logs  = __logf(ssum);
      float lpt   = (ltg - t1) - logs;
      float pt    = __expf(lpt);
      float om    = 1.f - pt;
      float focal = om * om * (-lpt);
      float ent   = logs - lsum * inv_s;
      float gap   = (1.f - __expf(t2 - t1)) * inv_s;
      float uq    = fmaxf(0.f, 1.f - gap);
      float mk    = (pz4[k] == 0) ? 1.f : 0.f;
      a_focal += focal * mk;
      a_ent   += ent * mk;
      a_msk   += mk;
      a_uniq  += uq;                           // uniqueness is unmasked
      float pm = inv_s * mk;

      u32* pw = (u32*)lbuf + (size_t)(4 * tid + k) * 9;   // [cell][9] in place
      pw[0] = pkrtz(e[0] * pm, e[1] * pm);
      pw[1] = pkrtz(e[2] * pm, e[3] * pm);
      pw[2] = pkrtz(e[4] * pm, e[5] * pm);
      pw[3] = pkrtz(e[6] * pm, e[7] * pm);
      pw[4] = pkrtz(e[8] * pm, 0.f);
    }
  }
}

static __device__ __forceinline__ void phaseC(
    const f4* lbuf, long c, int B, int tid, float& a_sq)
{
  if (tid < PB * 5) {                          // 60 lanes (wave 0), R8-proven
    const int pz = tid / 5, pr = tid - 5 * pz;
    if (c * PB + pz < (long)B) {
      const u32* cb = (const u32*)lbuf;
      h2 hz; hz[0] = (__fp16)0.f; hz[1] = (__fp16)0.f;
      h2 rs[9], cs[9], bs[9];
#pragma unroll
      for (int u = 0; u < 9; ++u) { rs[u] = hz; cs[u] = hz; bs[u] = hz; }
      const int base = pz * 729 + pr;          // word (pz*81+j)*9 + pr
#pragma unroll
      for (int j = 0; j < 81; ++j) {
        h2 v = __builtin_bit_cast(h2, cb[base + 9 * j]);
        rs[j / 9]                      += v;
        cs[j % 9]                      += v;
        bs[(j / 27) * 3 + (j % 9) / 3] += v;
      }
      const float hiw = (pr == 4) ? 0.f : 1.f; // pad class excluded
      float sq = 0.f;
#pragma unroll
      for (int u = 0; u < 9; ++u) {
        float x;
        x = (float)rs[u][0] - 1.f; sq = fmaf(x, x, sq);
        x = (float)cs[u][0] - 1.f; sq = fmaf(x, x, sq);
        x = (float)bs[u][0] - 1.f; sq = fmaf(x, x, sq);
        x = (float)rs[u][1] - 1.f; sq = fmaf(hiw * x, x, sq);
        x = (float)cs[u][1] - 1.f; sq = fmaf(hiw * x, x, sq);
        x = (float)bs[u][1] - 1.f; sq = fmaf(hiw * x, x, sq);
      }
      a_sq += sq;
    }
  }
}

__global__ __launch_bounds__(THREADS) void sudoku_main(
    const float* __restrict__ logits,
    const int*   __restrict__ targets,
    const int*   __restrict__ puzzles,
    float* __restrict__ partial,      // [5][grid]
    int B, long nchunk, int grid)
{
  __shared__ f4 bufA[PADF4];          // 36.9 KB
  __shared__ f4 bufB[PADF4];          // 36.9 KB
  __shared__ float sred[4][5];

  const int tid = threadIdx.x;
  const long totalCells = (long)B * 81;
  const long totF4 = totalCells * 9 / 4;
  const long maxCell0 = totalCells - 4;
  const long c0 = blockIdx.x;
  const long G = grid;

  float a_focal=0.f, a_ent=0.f, a_msk=0.f, a_uniq=0.f, a_sq=0.f;
  i4 tgA{}, pzA{}, tgB{}, pzB{};

  // ---- prologue: issue chunks c0 (bufA) and c0+G (bufB) ----
  issue_chunk((const f4*)logits, targets, puzzles, bufA, c0, totF4, maxCell0, tid, tgA, pzA);
  if (c0 + G < nchunk)
    issue_chunk((const f4*)logits, targets, puzzles, bufB, c0 + G, totF4, maxCell0, tid, tgB, pzB);

  for (long c = c0; c < nchunk; c += 2 * G) {
    // ---- half A: chunk c in bufA ----
    if (c + G < nchunk) WAITV11(); else WAITV0();   // c arrived; c+G stays in flight
    BAR();
    phaseA(bufA, tgA, pzA, c, totalCells, tid, a_focal, a_ent, a_msk, a_uniq);
    WAITL0(); BAR();
    phaseC(bufA, c, B, tid, a_sq);
    WAITL0(); BAR();                                // all waves done reading bufA
    if (c + 2 * G < nchunk)
      issue_chunk((const f4*)logits, targets, puzzles, bufA, c + 2 * G,
                  totF4, maxCell0, tid, tgA, pzA);

    // ---- half B: chunk c+G in bufB ----
    const long cb = c + G;
    if (cb < nchunk) {
      if (cb + G < nchunk) WAITV11(); else WAITV0();
      BAR();
      phaseA(bufB, tgB, pzB, cb, totalCells, tid, a_focal, a_ent, a_msk, a_uniq);
      WAITL0(); BAR();
      phaseC(bufB, cb, B, tid, a_sq);
      WAITL0(); BAR();
      if (cb + 2 * G < nchunk)
        issue_chunk((const f4*)logits, targets, puzzles, bufB, cb + 2 * G,
                    totF4, maxCell0, tid, tgB, pzB);
    }
  }

  // ---- wave + block reduction, transposed partial store (no atomics) ----
  const int wv = tid >> 6, lane = tid & 63;
#pragma unroll
  for (int off = 32; off > 0; off >>= 1) {
    a_focal += __shfl_down(a_focal, off);
    a_ent   += __shfl_down(a_ent,   off);
    a_msk   += __shfl_down(a_msk,   off);
    a_uniq  += __shfl_down(a_uniq,  off);
    a_sq    += __shfl_down(a_sq,    off);
  }
  if (lane == 0) {
    sred[wv][0] = a_focal; sred[wv][1] = a_ent; sred[wv][2] = a_msk;
    sred[wv][3] = a_uniq;  sred[wv][4] = a_sq;
  }
  __syncthreads();
  if (tid < 5) {
    float v = sred[0][tid] + sred[1][tid] + sred[2][tid] + sred[3][tid];
    partial[(size_t)tid * grid + blockIdx.x] = v;
  }
}

__global__ __launch_bounds__(1024) void sudoku_finalize(
    const float* __restrict__ partial, float* __restrict__ out,
    int ngrid, float invBG)
{
  __shared__ float sb[16][5];
  const int tid = threadIdx.x;
  float s[5] = {0.f, 0.f, 0.f, 0.f, 0.f};
  for (int b = tid; b < ngrid; b += 1024) {
#pragma unroll
    for (int u = 0; u < 5; ++u) s[u] += partial[(size_t)u * ngrid + b];
  }
#pragma unroll
  for (int off = 32; off > 0; off >>= 1)
#pragma unroll
    for (int u = 0; u < 5; ++u) s[u] += __shfl_down(s[u], off);
  const int wv = tid >> 6, lane = tid & 63;
  if (lane == 0) {
#pragma unroll
    for (int u = 0; u < 5; ++u) sb[wv][u] = s[u];
  }
  __syncthreads();
  if (tid == 0) {
    float focal = 0.f, ent = 0.f, msum = 0.f, uniq = 0.f, sq = 0.f;
#pragma unroll
    for (int w = 0; w < 16; ++w) {
      focal += sb[w][0]; ent += sb[w][1]; msum += sb[w][2];
      uniq  += sb[w][3]; sq  += sb[w][4];
    }
    float inv_m = 1.f / (msum + 1e-8f);
    float ce    = focal * inv_m;
    float entl  = 0.1f * ent * inv_m;
    float uql   = 0.1f * uniq * invBG;
    float rcb   = sq * invBG;        // row+col+box means share denominator B*81
    float constraint = (rcb + entl + uql) * 0.2f;
    out[0] = ce + 0.5f * constraint;
  }
}

extern "C" void kernel_launch(void* const* d_in, const int* in_sizes, int n_in,
                              void* d_out, int out_size, void* d_ws, size_t ws_size,
                              hipStream_t stream)
{
  (void)n_in; (void)out_size; (void)ws_size;
  const float* logits  = (const float*)d_in[0];
  const int*   targets = (const int*)d_in[1];
  const int*   puzzles = (const int*)d_in[2];
  float* out = (float*)d_out;
  float* partial = (float*)d_ws;

  const int B = in_sizes[0] / 729;               // B*9*9*9 logits
  const long totalCells = (long)B * 81;
  const long nchunk = (totalCells + CELLS_PB - 1) / CELLS_PB;   // 5462 @ B=65536
  const int grid = (int)(nchunk < MAXG ? nchunk : MAXG);

  sudoku_main<<<grid, THREADS, 0, stream>>>(logits, targets, puzzles, partial,
                                            B, nchunk, grid);

  const float invBG = 1.f / ((float)B * 81.f);
  sudoku_finalize<<<1, 1024, 0, stream>>>(partial, out, grid, invBG);
}

// Round 16
// 59.555 us; speedup vs baseline: 1.2173x; 1.1494x over previous
//
#include <hip/hip_runtime.h>

#define THREADS 256
#define PB 12                        // puzzles per block (no loop) — R8-proven
#define CELLS_PB (PB * 81)           // 972 cells
#define TOTW (CELLS_PB * 9)          // 8748 words staged (35 KB)
#define NF4 (TOTW / 4)               // 2187 float4
#define SLANES 243                   // staging + phase-A lanes (95% packing)

typedef float f4 __attribute__((ext_vector_type(4)));
typedef __fp16 h2 __attribute__((ext_vector_type(2)));
typedef unsigned int u32;
typedef int i4 __attribute__((ext_vector_type(4)));

#define LOG2E 1.44269504f
#define LN2   0.69314718f

static __device__ __forceinline__ u32 pkrtz(float a, float b) {
  h2 v = __builtin_amdgcn_cvt_pkrtz(a, b);     // v_cvt_pkrtz_f16_f32
  return __builtin_bit_cast(u32, v);
}

__global__ __launch_bounds__(THREADS) void sudoku_main(
    const float* __restrict__ logits,
    const int*   __restrict__ targets,
    const int*   __restrict__ puzzles,
    float* __restrict__ partial,      // [5][ngrid], per-block partials (no atomics)
    int B, int ngrid)
{
  __shared__ float buf[TOTW];         // staged logits f32 -> probs f16x2 in place
  __shared__ float sred[4][5];

  const int tid = threadIdx.x;
  const int g   = blockIdx.x;
  const long totalCells = (long)B * 81;
  const long lim4 = totalCells * 9 / 4;

  float a_focal=0.f, a_ent=0.f, a_msk=0.f, a_uniq=0.f, a_sq=0.f;

  // ---- stage logits: 243 lanes x 9 rounds of dense float4 (fully coalesced) ----
  if (tid < SLANES) {
    const f4* src = (const f4*)logits;
    const long b4 = (long)g * NF4;
    f4* dst = (f4*)buf;
#pragma unroll
    for (int r = 0; r < 9; ++r) {
      long idx = b4 + r * SLANES + tid;
      if (idx < lim4) dst[r * SLANES + tid] = src[idx];
    }
  }

  // ---- per-lane int loads: 4 cells as one int4 each (dense lines) ----
  const long cell0 = (long)g * CELLS_PB + 4 * tid;
  const bool vA = (tid < SLANES) && (cell0 < totalCells);
  i4 tg4{}, pz4{};
  if (vA) {
    tg4 = *(const i4*)(targets + cell0);
    pz4 = *(const i4*)(puzzles + cell0);
  }
  __syncthreads();

  // ---- phase A: read own 144B slice (9x b128), 4 cells in regs, exp2-domain ----
  if (vA) {
    f4 s[9];
#pragma unroll
    for (int q = 0; q < 9; ++q) s[q] = ((const f4*)buf)[tid * 9 + q];

#pragma unroll
    for (int k = 0; k < 4; ++k) {
      float l[9];
#pragma unroll
      for (int i = 0; i < 9; ++i) { const int w = 9 * k + i; l[i] = s[w >> 2][w & 3]; }
      int tg = tg4[k] - 1; tg = tg < 0 ? 0 : (tg > 8 ? 8 : tg);

      float t1 = l[0], t2 = -3.0e38f;            // branchless top-2 of logits
#pragma unroll
      for (int i = 1; i < 9; ++i) {
        float hi = fmaxf(t1, l[i]);
        float lo = fminf(t1, l[i]);
        t1 = hi; t2 = fmaxf(t2, lo);
      }
      const float t1b = t1 * LOG2E;
      float e[9], ssum = 0.f, lsum2 = 0.f, x2tg = 0.f;
#pragma unroll
      for (int i = 0; i < 9; ++i) {
        float x2 = fmaf(l[i], LOG2E, -t1b);      // (l-t1)*log2e
        float ei = __builtin_amdgcn_exp2f(x2);   // v_exp_f32 = 2^x
        e[i] = ei; ssum += ei;
        lsum2 = fmaf(ei, x2, lsum2);
        x2tg = (tg == i) ? x2 : x2tg;            // static-index select ladder
      }
      float inv_s = __builtin_amdgcn_rcpf(ssum);
      float logs2 = __builtin_amdgcn_logf(ssum); // v_log_f32 = log2
      float lptb  = x2tg - logs2;                // log2(p_target)
      float pt    = __builtin_amdgcn_exp2f(lptb);
      float om    = 1.f - pt;
      float focal = om * om * (-lptb * LN2);
      float ent   = (logs2 - lsum2 * inv_s) * LN2;
      float g2    = __builtin_amdgcn_exp2f(fmaf(t2, LOG2E, -t1b));   // exp(t2-t1)
      float gap   = (1.f - g2) * inv_s;
      float uq    = fmaxf(0.f, 1.f - gap);
      float mk    = (pz4[k] == 0) ? 1.f : 0.f;
      a_focal += focal * mk;
      a_ent   += ent * mk;
      a_msk   += mk;
      a_uniq  += uq;                             // uniqueness is unmasked
      float pm = inv_s * mk;

      u32* pw = (u32*)buf + (size_t)(4 * tid + k) * 9;   // [cell][9] in place
      pw[0] = pkrtz(e[0] * pm, e[1] * pm);
      pw[1] = pkrtz(e[2] * pm, e[3] * pm);
      pw[2] = pkrtz(e[4] * pm, e[5] * pm);
      pw[3] = pkrtz(e[6] * pm, e[7] * pm);
      pw[4] = pkrtz(e[8] * pm, 0.f);
    }
  }
  __syncthreads();

  // ---- phase C: 60 workers spread over ALL 4 waves (15 lanes/wave) ----
  // bank check: word addr pz*729+pr+9j, lanes' (25*pz+pr)%32 all distinct -> conflict-free
  const int wv = tid >> 6, lane = tid & 63;
  if (lane < 15) {
    const int pz = wv * 3 + lane / 5;            // 0..11
    const int pr = lane % 5;
    if ((long)g * PB + pz < (long)B) {
      const u32* cb = (const u32*)buf;
      h2 hz; hz[0] = (__fp16)0.f; hz[1] = (__fp16)0.f;
      h2 rs[9], cs[9], bs[9];
#pragma unroll
      for (int u = 0; u < 9; ++u) { rs[u] = hz; cs[u] = hz; bs[u] = hz; }
      const int base = pz * 729 + pr;            // word (pz*81+j)*9 + pr
#pragma unroll
      for (int j = 0; j < 81; ++j) {
        h2 v = __builtin_bit_cast(h2, cb[base + 9 * j]);
        rs[j / 9]                      += v;
        cs[j % 9]                      += v;
        bs[(j / 27) * 3 + (j % 9) / 3] += v;
      }
      const float hiw = (pr == 4) ? 0.f : 1.f;   // pad class excluded
      float sq = 0.f;
#pragma unroll
      for (int u = 0; u < 9; ++u) {
        float x;
        x = (float)rs[u][0] - 1.f; sq = fmaf(x, x, sq);
        x = (float)cs[u][0] - 1.f; sq = fmaf(x, x, sq);
        x = (float)bs[u][0] - 1.f; sq = fmaf(x, x, sq);
        x = (float)rs[u][1] - 1.f; sq = fmaf(hiw * x, x, sq);
        x = (float)cs[u][1] - 1.f; sq = fmaf(hiw * x, x, sq);
        x = (float)bs[u][1] - 1.f; sq = fmaf(hiw * x, x, sq);
      }
      a_sq += sq;
    }
  }

  // ---- wave + block reduction, transposed partial store (no atomics) ----
#pragma unroll
  for (int off = 32; off > 0; off >>= 1) {
    a_focal += __shfl_down(a_focal, off);
    a_ent   += __shfl_down(a_ent,   off);
    a_msk   += __shfl_down(a_msk,   off);
    a_uniq  += __shfl_down(a_uniq,  off);
    a_sq    += __shfl_down(a_sq,    off);
  }
  if (lane == 0) {
    sred[wv][0] = a_focal; sred[wv][1] = a_ent; sred[wv][2] = a_msk;
    sred[wv][3] = a_uniq;  sred[wv][4] = a_sq;
  }
  __syncthreads();
  if (tid < 5) {
    float v = sred[0][tid] + sred[1][tid] + sred[2][tid] + sred[3][tid];
    partial[(size_t)tid * ngrid + g] = v;
  }
}

__global__ __launch_bounds__(1024) void sudoku_finalize(
    const float* __restrict__ partial, float* __restrict__ out,
    int ngrid, float invBG)
{
  __shared__ float sb[16][5];
  const int tid = threadIdx.x;
  float s[5] = {0.f, 0.f, 0.f, 0.f, 0.f};
  for (int b = tid; b < ngrid; b += 1024) {
#pragma unroll
    for (int u = 0; u < 5; ++u) s[u] += partial[(size_t)u * ngrid + b];   // coalesced
  }
#pragma unroll
  for (int off = 32; off > 0; off >>= 1)
#pragma unroll
    for (int u = 0; u < 5; ++u) s[u] += __shfl_down(s[u], off);
  const int wv = tid >> 6, lane = tid & 63;
  if (lane == 0) {
#pragma unroll
    for (int u = 0; u < 5; ++u) sb[wv][u] = s[u];
  }
  __syncthreads();
  if (tid == 0) {
    float focal = 0.f, ent = 0.f, msum = 0.f, uniq = 0.f, sq = 0.f;
#pragma unroll
    for (int w = 0; w < 16; ++w) {
      focal += sb[w][0]; ent += sb[w][1]; msum += sb[w][2];
      uniq  += sb[w][3]; sq  += sb[w][4];
    }
    float inv_m = 1.f / (msum + 1e-8f);
    float ce    = focal * inv_m;
    float entl  = 0.1f * ent * inv_m;
    float uql   = 0.1f * uniq * invBG;
    float rcb   = sq * invBG;        // row+col+box means share denominator B*81
    float constraint = (rcb + entl + uql) * 0.2f;
    out[0] = ce + 0.5f * constraint;
  }
}

extern "C" void kernel_launch(void* const* d_in, const int* in_sizes, int n_in,
                              void* d_out, int out_size, void* d_ws, size_t ws_size,
                              hipStream_t stream)
{
  (void)n_in; (void)out_size; (void)ws_size;
  const float* logits  = (const float*)d_in[0];
  const int*   targets = (const int*)d_in[1];
  const int*   puzzles = (const int*)d_in[2];
  float* out = (float*)d_out;
  float* partial = (float*)d_ws;

  const int B = in_sizes[0] / 729;               // B*9*9*9 logits
  const long totalCells = (long)B * 81;
  const int ngrid = (int)((totalCells + CELLS_PB - 1) / CELLS_PB);   // 5462 @ B=65536

  sudoku_main<<<ngrid, THREADS, 0, stream>>>(logits, targets, puzzles, partial, B, ngrid);

  const float invBG = 1.f / ((float)B * 81.f);
  sudoku_finalize<<<1, 1024, 0, stream>>>(partial, out, ngrid, invBG);
}